// Round 1
// baseline (457.819 us; speedup 1.0000x reference)
//
#include <hip/hip_runtime.h>
#include <hip/hip_bf16.h>

#define Nn 8192
#define Dd 512
#define KK 16
#define CC 32      // candidates kept per partial list / merged list
#define TI 128
#define TJ 128
#define BKc 64
#define JSPLIT 8
#define JTILES (Nn / JSPLIT / TJ)   // 8
#define PARTS (JSPLIT * 2)          // 16 partial lists per row

typedef short bf16x8 __attribute__((ext_vector_type(8)));
typedef float f32x4 __attribute__((ext_vector_type(4)));
typedef unsigned int uint32;

// Insert v into a descending-sorted 32-entry register array (h[0] = largest).
// Precondition: v < h[0]. Single bubble pass restores sorted order.
__device__ __forceinline__ void heap_insert32(uint32* h, uint32 v) {
  h[0] = v;
#pragma unroll
  for (int s = 0; s < CC - 1; ++s) {
    uint32 a = h[s], b = h[s + 1];
    uint32 mx = a > b ? a : b;
    uint32 mn = a > b ? b : a;
    h[s] = mx;
    h[s + 1] = mn;
  }
}

// Async global->LDS, 16B per lane. LDS dest must be wave-uniform base (+lane*16 is HW-applied).
__device__ __forceinline__ void gload_lds16(const void* g, void* l) {
  __builtin_amdgcn_global_load_lds(
      (const __attribute__((address_space(1))) unsigned int*)g,
      (__attribute__((address_space(3))) unsigned int*)l, 16, 0, 0);
}

// ---------------- Kernel A: fp32 -> bf16 copy + row sq-norms ----------------
__global__ void knn_prep(const float* __restrict__ x, uint32* __restrict__ xbu,
                         float* __restrict__ sq) {
  const int row = blockIdx.x * 4 + (threadIdx.x >> 6);
  const int l = threadIdx.x & 63;
  const float2* xr = (const float2*)(x + (size_t)row * Dd);
  float s = 0.f;
#pragma unroll
  for (int q = 0; q < 4; ++q) {
    float2 v = xr[q * 64 + l];
    s = fmaf(v.x, v.x, s);
    s = fmaf(v.y, v.y, s);
    uint32 ux = __builtin_bit_cast(uint32, v.x);
    uint32 uy = __builtin_bit_cast(uint32, v.y);
    uint32 bx = (ux + 0x7FFFu + ((ux >> 16) & 1u)) >> 16;  // RNE to bf16
    uint32 by = (uy + 0x7FFFu + ((uy >> 16) & 1u)) >> 16;
    xbu[(size_t)row * (Dd / 2) + q * 64 + l] = bx | (by << 16);
  }
#pragma unroll
  for (int off = 32; off > 0; off >>= 1) s += __shfl_down(s, off);
  if (l == 0) sq[row] = s;
}

// ------- Kernel B: fused bf16-MFMA Gram tile + per-row top-32 candidates -------
__global__ __launch_bounds__(256, 2) void knn_cand(
    const unsigned short* __restrict__ xb, const float* __restrict__ sq,
    uint32* __restrict__ partials) {
  __shared__ unsigned short ALds[TI * BKc];  // 16 KB
  __shared__ unsigned short BLds[TJ * BKc];  // 16 KB
  __shared__ float d2s[TI][64];              // 32 KB (one 64-col phase at a time)
  __shared__ float sqj[TJ];

  const int bid = blockIdx.x;
  const int ib = bid & 63;  // 64 I-tiles
  const int jc = bid >> 6;  // 8 J-chunks
  const int t = threadIdx.x;
  const int w = t >> 6;
  const int l = t & 63;
  const int wrow = w >> 1, wcol = w & 1;
  const int l16 = l & 15, lq = l >> 4;

  const int row_s = t >> 1;  // scan: thread's row within tile
  const int hv = t & 1;      // scan: which 32-col half
  const int irow_g = ib * TI + row_s;

  uint32 heap[CC];
#pragma unroll
  for (int s = 0; s < CC; ++s) heap[s] = 0xFFFFFFFFu;

  for (int jt = 0; jt < JTILES; ++jt) {
    const int jbase = jc * (Nn / JSPLIT) + jt * TJ;
    __syncthreads();  // previous scan's sqj reads done
    if (t < TJ) sqj[t] = sq[jbase + t];

    f32x4 acc[4][4];
#pragma unroll
    for (int a = 0; a < 4; ++a)
#pragma unroll
      for (int b = 0; b < 4; ++b) acc[a][b] = (f32x4){0.f, 0.f, 0.f, 0.f};

    for (int kk = 0; kk < Dd / BKc; ++kk) {
      __syncthreads();  // LDS reads of previous chunk done
#pragma unroll
      for (int u = 0; u < 4; ++u) {
        const int ch = w * 4 + u;          // wave-uniform chunk id (1KB each)
        const int r = ch * 8 + (l >> 3);   // row within tile
        const int col = (l & 7) * 8;       // bf16 col within BK
        gload_lds16(xb + (size_t)(ib * TI + r) * Dd + kk * BKc + col,
                    (void*)(ALds + ch * 512));
        gload_lds16(xb + (size_t)(jbase + r) * Dd + kk * BKc + col,
                    (void*)(BLds + ch * 512));
      }
      __syncthreads();  // staging complete (vmcnt drained by barrier)
#pragma unroll
      for (int ks = 0; ks < 2; ++ks) {
        bf16x8 af[4], bfr[4];
#pragma unroll
        for (int fi = 0; fi < 4; ++fi)
          af[fi] = *(const bf16x8*)&ALds[(wrow * 64 + fi * 16 + l16) * BKc +
                                         ks * 32 + lq * 8];
#pragma unroll
        for (int fj = 0; fj < 4; ++fj)
          bfr[fj] = *(const bf16x8*)&BLds[(wcol * 64 + fj * 16 + l16) * BKc +
                                          ks * 32 + lq * 8];
#pragma unroll
        for (int fi = 0; fi < 4; ++fi)
#pragma unroll
          for (int fj = 0; fj < 4; ++fj)
            acc[fi][fj] = __builtin_amdgcn_mfma_f32_16x16x32_bf16(
                af[fi], bfr[fj], acc[fi][fj], 0, 0, 0);
      }
    }

    // Two 64-col phases: stage dot products to LDS, scan into register top-32.
    for (int p = 0; p < 2; ++p) {
      __syncthreads();  // previous phase's scan reads done
      if (wcol == p) {
#pragma unroll
        for (int fi = 0; fi < 4; ++fi)
#pragma unroll
          for (int fj = 0; fj < 4; ++fj)
#pragma unroll
            for (int r = 0; r < 4; ++r)
              d2s[wrow * 64 + fi * 16 + lq * 4 + r][fj * 16 + l16] =
                  acc[fi][fj][r];
      }
      __syncthreads();
      const int c0 = hv * 32;
#pragma unroll
      for (int u2 = 0; u2 < 8; ++u2) {
        float4 v = *(const float4*)&d2s[row_s][c0 + u2 * 4];
        float vv[4] = {v.x, v.y, v.z, v.w};
#pragma unroll
        for (int e = 0; e < 4; ++e) {
          const int jj = c0 + u2 * 4 + e;
          const int jg = jbase + p * 64 + jj;
          // key = d2 - sq_i (constant per row dropped): sq_j - 2*dot
          float key = fmaf(-2.f, vv[e], sqj[p * 64 + jj]);
          uint32 ub = __builtin_bit_cast(uint32, key);
          uint32 m = ub ^ ((ub >> 31) ? 0xFFFFFFFFu : 0x80000000u);  // order-preserving
          uint32 packed = (m & 0xFFFFE000u) | (uint32)jg;            // 13-bit index
          if (jg == irow_g) packed = 0xFFFFFFFFu;                    // exclude self
          if (packed < heap[0]) heap_insert32(heap, packed);
        }
      }
    }
  }

  const int part = jc * 2 + hv;
#pragma unroll
  for (int s = 0; s < CC; ++s)
    partials[(size_t)(part * CC + s) * Nn + irow_g] = heap[s];
}

// ---------------- Kernel C: merge 16 partial lists -> top-32 per row ----------------
__global__ void knn_merge(const uint32* __restrict__ partials,
                          int* __restrict__ cand) {
  const int row = blockIdx.x * 256 + threadIdx.x;
  uint32 heap[CC];
#pragma unroll
  for (int s = 0; s < CC; ++s) heap[s] = 0xFFFFFFFFu;
  for (int p = 0; p < PARTS * CC; ++p) {
    uint32 v = partials[(size_t)p * Nn + row];
    if (v < heap[0]) heap_insert32(heap, v);
  }
#pragma unroll
  for (int s = 0; s < CC; ++s)
    cand[(size_t)row * CC + s] = (int)(heap[s] & 0x1FFFu);
}

// ------- Kernel D: exact fp64 rescore of 32 candidates -> top-16 -> average -------
__global__ void knn_rescore(const float* __restrict__ x,
                            const int* __restrict__ cand,
                            float* __restrict__ out) {
  __shared__ int candS[CC];
  __shared__ double d2S[CC];
  __shared__ int selS[KK];
  const int row = blockIdx.x;
  const int t = threadIdx.x, w = t >> 6, l = t & 63;
  if (t < CC) candS[t] = cand[(size_t)row * CC + t];
  __syncthreads();
  float xi[8];
#pragma unroll
  for (int q = 0; q < 8; ++q) xi[q] = x[(size_t)row * Dd + q * 64 + l];
  for (int u = 0; u < 8; ++u) {
    const int c = w * 8 + u;
    const int j = candS[c];
    double s = 0.0;
#pragma unroll
    for (int q = 0; q < 8; ++q) {
      double d = (double)xi[q] - (double)x[(size_t)j * Dd + q * 64 + l];
      s = fma(d, d, s);
    }
#pragma unroll
    for (int off = 32; off > 0; off >>= 1) s += __shfl_down(s, off);
    if (l == 0) d2S[c] = s;
  }
  __syncthreads();
  if (t < CC) {
    const double mine = d2S[t];
    const int mi = candS[t];
    int rank = 0;
#pragma unroll
    for (int o = 0; o < CC; ++o) {
      double vo = d2S[o];
      int io = candS[o];
      if (vo < mine || (vo == mine && io < mi)) rank++;
    }
    if (rank < KK) selS[rank] = mi;
  }
  __syncthreads();
#pragma unroll
  for (int h = 0; h < 2; ++h) {
    const int d = t + h * 256;
    float a = 0.f;
#pragma unroll
    for (int n = 0; n < KK; ++n) a += x[(size_t)selS[n] * Dd + d];
    out[(size_t)row * Dd + d] = a * 0.0625f;
  }
}

extern "C" void kernel_launch(void* const* d_in, const int* in_sizes, int n_in,
                              void* d_out, int out_size, void* d_ws,
                              size_t ws_size, hipStream_t stream) {
  const float* x = (const float*)d_in[0];
  float* out = (float*)d_out;
  char* ws = (char*)d_ws;
  // ws layout: xb (8MB) | sq (32KB) | partials (16MB) | cand (1MB)  => ~25.2MB
  unsigned short* xb = (unsigned short*)ws;
  float* sq = (float*)(ws + (size_t)Nn * Dd * 2);
  uint32* partials = (uint32*)(ws + (size_t)Nn * Dd * 2 + (size_t)Nn * 4);
  int* cand = (int*)((char*)partials + (size_t)PARTS * CC * Nn * 4);

  knn_prep<<<Nn / 4, 256, 0, stream>>>(x, (uint32*)xb, sq);
  knn_cand<<<64 * JSPLIT, 256, 0, stream>>>(xb, sq, partials);
  knn_merge<<<Nn / 256, 256, 0, stream>>>(partials, cand);
  knn_rescore<<<Nn, 256, 0, stream>>>(x, cand, out);
}